// Round 1
// baseline (3308.754 us; speedup 1.0000x reference)
//
#include <hip/hip_runtime.h>

// SAGE_876173328847: 2-layer bipartite SAGEConv (mean agg) + log_softmax.
// N0=200000, N1=100000, N2=20000, E1=1.6M, E2=320K, D_IN=128, D_H=256, D_OUT=64.
//
// Strategy:
//   agg1 = segment_mean(x[src1], dst1, N1)            (atomic scatter, 128-wide)
//   h1   = relu([agg1 | x[:N1]] @ [W_l1|W_r1]^T + b1)  (fused fp32 GEMM, K=256)
//   t2   = h1 @ W_l2^T                                 (premultiply BEFORE aggregating:
//                                                       mean/matmul commute -> scatter 64-wide not 256-wide)
//   agg2 = segment_mean(t2[src2], dst2, N2)            (atomic scatter, 64-wide)
//   out  = log_softmax(agg2 + b2 + h1[:N2] @ W_r2^T)

#define CN0 200000
#define CN1 100000
#define CN2 20000
#define CE1 1600000
#define CE2 320000
#define CD_IN 128
#define CD_H 256
#define CD_OUT 64

// ---------------- scatter: agg1 += x[src], cnt1 += 1 ----------------
// 32 lanes per edge, one float4 per lane (128 floats).
__global__ __launch_bounds__(256) void sage_scatter1(
    const float* __restrict__ x, const int* __restrict__ src,
    const int* __restrict__ dst, float* __restrict__ agg, float* __restrict__ cnt) {
  int idx = blockIdx.x * 256 + threadIdx.x;
  int e = idx >> 5;
  int c = idx & 31;
  if (e >= CE1) return;
  int s = src[e];
  int d = dst[e];
  float4 v = reinterpret_cast<const float4*>(x)[s * 32 + c];
  float* o = agg + (size_t)d * CD_IN + c * 4;
  atomicAdd(o + 0, v.x);
  atomicAdd(o + 1, v.y);
  atomicAdd(o + 2, v.z);
  atomicAdd(o + 3, v.w);
  if (c == 0) atomicAdd(cnt + d, 1.0f);
}

// ---------------- scatter: agg2 += t2[src], cnt2 += 1 ----------------
// 16 lanes per edge, one float4 per lane (64 floats).
__global__ __launch_bounds__(256) void sage_scatter2(
    const float* __restrict__ t2, const int* __restrict__ src,
    const int* __restrict__ dst, float* __restrict__ agg, float* __restrict__ cnt) {
  int idx = blockIdx.x * 256 + threadIdx.x;
  int e = idx >> 4;
  int c = idx & 15;
  if (e >= CE2) return;
  int s = src[e];
  int d = dst[e];
  float4 v = reinterpret_cast<const float4*>(t2)[s * 16 + c];
  float* o = agg + (size_t)d * CD_OUT + c * 4;
  atomicAdd(o + 0, v.x);
  atomicAdd(o + 1, v.y);
  atomicAdd(o + 2, v.z);
  atomicAdd(o + 3, v.w);
  if (c == 0) atomicAdd(cnt + d, 1.0f);
}

// ---------------- gemm1: h1 = relu([agg_mean | x] @ [W_l1|W_r1]^T + b) ----------------
// grid (ceil(N1/64), 2). block 256. Tile: 64 rows x 128 cols, KT=16, micro 4x8.
__global__ __launch_bounds__(256) void sage_gemm1(
    const float* __restrict__ agg, const float* __restrict__ cnt,
    const float* __restrict__ x, const float* __restrict__ Wl,
    const float* __restrict__ Wr, const float* __restrict__ b,
    float* __restrict__ h1) {
  __shared__ float As[16][68];    // [k][row], pad to keep float4 alignment + spread banks
  __shared__ float Ws[16][132];   // [k][col]
  const int row0 = blockIdx.x * 64;
  const int col0 = blockIdx.y * 128;
  const int tid = threadIdx.x;
  const int tcol = tid & 15;   // owns cols col0 + tcol*8 .. +7
  const int trow = tid >> 4;   // owns rows row0 + trow*4 .. +3

  // A staging mapping: 64 rows x 16 k = 1024 floats = 256 float4 (1/thread)
  const int arow = tid >> 2;          // 0..63
  const int ag = tid & 3;             // float4 group within 16 k
  int grow = row0 + arow;
  int growc = grow < CN1 ? grow : CN1 - 1;
  const float ic = 1.0f / fmaxf(cnt[growc], 1.0f);

  // W staging mapping: 128 cols x 16 k = 512 float4 (2/thread)
  const int wrow = tid >> 1;              // 0..127
  const int wg0 = (tid & 1) * 2;          // float4 groups {0,1} or {2,3}
  const int jglob = col0 + wrow;

  float acc[4][8] = {};

  for (int t = 0; t < 16; ++t) {
    const int kk = (t & 7) * 16;
    const float* Asrc = (t < 8) ? agg : x;
    const float* Wsrc = (t < 8) ? Wl : Wr;
    const float sc = (t < 8) ? ic : 1.0f;

    float4 av = reinterpret_cast<const float4*>(Asrc + (size_t)growc * CD_IN + kk)[ag];
    const float4* wp = reinterpret_cast<const float4*>(Wsrc + (size_t)jglob * CD_IN + kk);
    float4 w0 = wp[wg0];
    float4 w1 = wp[wg0 + 1];

    __syncthreads();
    As[ag * 4 + 0][arow] = av.x * sc;
    As[ag * 4 + 1][arow] = av.y * sc;
    As[ag * 4 + 2][arow] = av.z * sc;
    As[ag * 4 + 3][arow] = av.w * sc;
    Ws[wg0 * 4 + 0][wrow] = w0.x;
    Ws[wg0 * 4 + 1][wrow] = w0.y;
    Ws[wg0 * 4 + 2][wrow] = w0.z;
    Ws[wg0 * 4 + 3][wrow] = w0.w;
    Ws[wg0 * 4 + 4][wrow] = w1.x;
    Ws[wg0 * 4 + 5][wrow] = w1.y;
    Ws[wg0 * 4 + 6][wrow] = w1.z;
    Ws[wg0 * 4 + 7][wrow] = w1.w;
    __syncthreads();

#pragma unroll
    for (int k = 0; k < 16; ++k) {
      float4 a = *reinterpret_cast<const float4*>(&As[k][trow * 4]);
      float4 u0 = *reinterpret_cast<const float4*>(&Ws[k][tcol * 8]);
      float4 u1 = *reinterpret_cast<const float4*>(&Ws[k][tcol * 8 + 4]);
      float avv[4] = {a.x, a.y, a.z, a.w};
      float wvv[8] = {u0.x, u0.y, u0.z, u0.w, u1.x, u1.y, u1.z, u1.w};
#pragma unroll
      for (int r = 0; r < 4; ++r)
#pragma unroll
        for (int c = 0; c < 8; ++c)
          acc[r][c] = fmaf(avv[r], wvv[c], acc[r][c]);
    }
  }

  // epilogue: bias + relu, float4 stores
  const int gc = col0 + tcol * 8;
  float4 b0 = *reinterpret_cast<const float4*>(b + gc);
  float4 b1 = *reinterpret_cast<const float4*>(b + gc + 4);
  float bv[8] = {b0.x, b0.y, b0.z, b0.w, b1.x, b1.y, b1.z, b1.w};
#pragma unroll
  for (int r = 0; r < 4; ++r) {
    int gr = row0 + trow * 4 + r;
    if (gr < CN1) {
      float4 o0, o1;
      o0.x = fmaxf(acc[r][0] + bv[0], 0.0f);
      o0.y = fmaxf(acc[r][1] + bv[1], 0.0f);
      o0.z = fmaxf(acc[r][2] + bv[2], 0.0f);
      o0.w = fmaxf(acc[r][3] + bv[3], 0.0f);
      o1.x = fmaxf(acc[r][4] + bv[4], 0.0f);
      o1.y = fmaxf(acc[r][5] + bv[5], 0.0f);
      o1.z = fmaxf(acc[r][6] + bv[6], 0.0f);
      o1.w = fmaxf(acc[r][7] + bv[7], 0.0f);
      float* op = &h1[(size_t)gr * CD_H + gc];
      *reinterpret_cast<float4*>(op) = o0;
      *reinterpret_cast<float4*>(op + 4) = o1;
    }
  }
}

// ---------------- gemm_nk64: out[M,64] = A[M,256] @ W[64,256]^T ----------------
// grid ceil(M/64). block 256. KT=32, micro 4x4.
__global__ __launch_bounds__(256) void sage_gemm_nk64(
    const float* __restrict__ A, const float* __restrict__ W,
    float* __restrict__ out, int M) {
  __shared__ float As[32][68];
  __shared__ float Ws[32][68];
  const int row0 = blockIdx.x * 64;
  const int tid = threadIdx.x;
  const int tc = tid & 15;   // owns cols tc*4 .. +3
  const int tr = tid >> 4;   // owns rows row0 + tr*4 .. +3

  float acc[4][4] = {};

  for (int t = 0; t < 8; ++t) {
    const int kk = t * 32;
    float4 va[2], vw[2];
    int rr[2], gg[2];
#pragma unroll
    for (int i = 0; i < 2; ++i) {
      int q = tid + 256 * i;     // 0..511
      int r = q >> 3;            // 0..63
      int g = q & 7;             // float4 group within 32 k
      rr[i] = r; gg[i] = g;
      int gr = row0 + r;
      int grc = gr < M ? gr : M - 1;
      va[i] = reinterpret_cast<const float4*>(A + (size_t)grc * CD_H + kk)[g];
      vw[i] = reinterpret_cast<const float4*>(W + (size_t)r * CD_H + kk)[g];
    }
    __syncthreads();
#pragma unroll
    for (int i = 0; i < 2; ++i) {
      int r = rr[i], g = gg[i];
      As[g * 4 + 0][r] = va[i].x;
      As[g * 4 + 1][r] = va[i].y;
      As[g * 4 + 2][r] = va[i].z;
      As[g * 4 + 3][r] = va[i].w;
      Ws[g * 4 + 0][r] = vw[i].x;
      Ws[g * 4 + 1][r] = vw[i].y;
      Ws[g * 4 + 2][r] = vw[i].z;
      Ws[g * 4 + 3][r] = vw[i].w;
    }
    __syncthreads();

#pragma unroll
    for (int k = 0; k < 32; ++k) {
      float4 a = *reinterpret_cast<const float4*>(&As[k][tr * 4]);
      float4 w = *reinterpret_cast<const float4*>(&Ws[k][tc * 4]);
      float avv[4] = {a.x, a.y, a.z, a.w};
      float wvv[4] = {w.x, w.y, w.z, w.w};
#pragma unroll
      for (int r = 0; r < 4; ++r)
#pragma unroll
        for (int c = 0; c < 4; ++c)
          acc[r][c] = fmaf(avv[r], wvv[c], acc[r][c]);
    }
  }

#pragma unroll
  for (int r = 0; r < 4; ++r) {
    int gr = row0 + tr * 4 + r;
    if (gr < M) {
      float4 o;
      o.x = acc[r][0]; o.y = acc[r][1]; o.z = acc[r][2]; o.w = acc[r][3];
      *reinterpret_cast<float4*>(&out[(size_t)gr * CD_OUT + tc * 4]) = o;
    }
  }
}

// ---------------- finalize: out = log_softmax(out + agg2_mean + b2) ----------------
// 4 rows/block, one 64-lane wave per row.
__global__ __launch_bounds__(256) void sage_finalize(
    const float* __restrict__ agg2, const float* __restrict__ cnt2,
    const float* __restrict__ b, float* __restrict__ out) {
  int row = blockIdx.x * 4 + (threadIdx.x >> 6);
  int lane = threadIdx.x & 63;
  if (row >= CN2) return;
  float ic = 1.0f / fmaxf(cnt2[row], 1.0f);
  size_t o = (size_t)row * CD_OUT + lane;
  float v = out[o] + agg2[o] * ic + b[lane];
  float m = v;
#pragma unroll
  for (int d = 32; d > 0; d >>= 1) m = fmaxf(m, __shfl_xor(m, d));
  float e = expf(v - m);
  float s = e;
#pragma unroll
  for (int d = 32; d > 0; d >>= 1) s += __shfl_xor(s, d);
  out[o] = v - m - logf(s);
}

extern "C" void kernel_launch(void* const* d_in, const int* in_sizes, int n_in,
                              void* d_out, int out_size, void* d_ws, size_t ws_size,
                              hipStream_t stream) {
  const float* x    = (const float*)d_in[0];
  const int* src1   = (const int*)d_in[1];
  const int* dst1   = (const int*)d_in[2];
  const int* src2   = (const int*)d_in[3];
  const int* dst2   = (const int*)d_in[4];
  const float* W_l1 = (const float*)d_in[5];
  const float* b_l1 = (const float*)d_in[6];
  const float* W_r1 = (const float*)d_in[7];
  const float* W_l2 = (const float*)d_in[8];
  const float* b_l2 = (const float*)d_in[9];
  const float* W_r2 = (const float*)d_in[10];
  float* out = (float*)d_out;
  float* ws = (float*)d_ws;

  // workspace layout (floats):
  //   [agg1: N1*128 | cnt1: N1 | agg2: N2*64 | cnt2: N2 | h1: N1*256]
  //   t2 (N1*64) aliases agg1 (dead after gemm1; 6.4M <= 12.8M floats).
  float* agg1 = ws;
  float* cnt1 = agg1 + (size_t)CN1 * CD_IN;
  float* agg2 = cnt1 + CN1;
  float* cnt2 = agg2 + (size_t)CN2 * CD_OUT;
  float* h1   = cnt2 + CN2;
  float* t2   = agg1;  // alias

  size_t zero_floats = (size_t)CN1 * CD_IN + CN1 + (size_t)CN2 * CD_OUT + CN2;
  size_t need_bytes = (zero_floats + (size_t)CN1 * CD_H) * 4;
  if (ws_size < need_bytes) return;  // refuse to corrupt memory

  hipMemsetAsync(ws, 0, zero_floats * 4, stream);

  sage_scatter1<<<(CE1 * 32) / 256, 256, 0, stream>>>(x, src1, dst1, agg1, cnt1);

  sage_gemm1<<<dim3((CN1 + 63) / 64, 2), 256, 0, stream>>>(
      agg1, cnt1, x, W_l1, W_r1, b_l1, h1);

  sage_gemm_nk64<<<(CN1 + 63) / 64, 256, 0, stream>>>(h1, W_l2, t2, CN1);

  sage_scatter2<<<(CE2 * 16) / 256, 256, 0, stream>>>(t2, src2, dst2, agg2, cnt2);

  sage_gemm_nk64<<<(CN2 + 63) / 64, 256, 0, stream>>>(h1, W_r2, out, CN2);

  sage_finalize<<<(CN2 + 3) / 4, 256, 0, stream>>>(agg2, cnt2, b_l2, out);
}

// Round 2
// 667.486 us; speedup vs baseline: 4.9570x; 4.9570x over previous
//
#include <hip/hip_runtime.h>

// SAGE_876173328847: 2-layer bipartite SAGEConv (mean agg) + log_softmax.
// N0=200000, N1=100000, N2=20000, E1=1.6M, E2=320K, D_IN=128, D_H=256, D_OUT=64.
//
// R1: replace atomic scatter-mean (was 83% of runtime, atomic-bound at 74G atomics/s)
// with on-the-fly CSR build (counting sort by dst) + gather-reduce. Zero float atomics.
//
//   CSR1: deg1/R1/cur1/esrc1 built from (src1,dst1)
//   agg1 = gather_mean(x, CSR1)                       (128 threads/dst, coalesced)
//   h1   = relu([agg1 | x[:N1]] @ [W_l1|W_r1]^T + b1) (fused fp32 GEMM, K=256)
//   t2   = h1 @ W_l2^T                                (premultiply: mean/matmul commute)
//   agg2 = gather_mean(t2, CSR2)                      (64 threads/dst)
//   out  = log_softmax(agg2 + b2 + h1[:N2] @ W_r2^T)

#define CN0 200000
#define CN1 100000
#define CN2 20000
#define CE1 1600000
#define CE2 320000
#define CD_IN 128
#define CD_H 256
#define CD_OUT 64

// ---------------- CSR build ----------------
__global__ __launch_bounds__(256) void sage_hist(
    const int* __restrict__ dst, int* __restrict__ deg, int E) {
  int e = blockIdx.x * 256 + threadIdx.x;
  if (e < E) atomicAdd(&deg[dst[e]], 1);
}

// per-block exclusive scan of 512 elements; writes block total to part[b]
__global__ __launch_bounds__(256) void sage_scan_local(
    const int* __restrict__ deg, int* __restrict__ R, int* __restrict__ part, int N) {
  __shared__ int sm[256];
  int t = threadIdx.x;
  int base = blockIdx.x * 512;
  int i0 = base + 2 * t, i1 = base + 2 * t + 1;
  int a = (i0 < N) ? deg[i0] : 0;
  int b = (i1 < N) ? deg[i1] : 0;
  int s = a + b;
  sm[t] = s;
  __syncthreads();
#pragma unroll
  for (int off = 1; off < 256; off <<= 1) {
    int v = (t >= off) ? sm[t - off] : 0;
    __syncthreads();
    sm[t] += v;
    __syncthreads();
  }
  int excl = sm[t] - s;
  if (i0 < N) R[i0] = excl;
  if (i1 < N) R[i1] = excl + a;
  if (t == 255) part[blockIdx.x] = sm[255];
}

__global__ void sage_scan_part(int* __restrict__ part, int B) {
  if (threadIdx.x == 0 && blockIdx.x == 0) {
    int acc = 0;
    for (int i = 0; i < B; ++i) { int v = part[i]; part[i] = acc; acc += v; }
  }
}

__global__ __launch_bounds__(256) void sage_addback(
    int* __restrict__ R, int* __restrict__ cur, const int* __restrict__ part, int N) {
  int i = blockIdx.x * 256 + threadIdx.x;
  if (i < N) { int v = R[i] + part[i >> 9]; R[i] = v; cur[i] = v; }
}

__global__ __launch_bounds__(256) void sage_place(
    const int* __restrict__ src, const int* __restrict__ dst,
    int* __restrict__ cur, int* __restrict__ esrc, int E) {
  int e = blockIdx.x * 256 + threadIdx.x;
  if (e < E) {
    int p = atomicAdd(&cur[dst[e]], 1);
    esrc[p] = src[e];
  }
}

// ---------------- gather-mean, 128 threads per dst (layer 1) ----------------
__global__ __launch_bounds__(256) void sage_gather1(
    const float* __restrict__ x, const int* __restrict__ esrc,
    const int* __restrict__ R, const int* __restrict__ deg,
    float* __restrict__ agg) {
  int d = blockIdx.x * 2 + (threadIdx.x >> 7);
  int c = threadIdx.x & 127;
  if (d >= CN1) return;
  int start = R[d], n = deg[d];
  float acc = 0.0f;
  int i = 0;
  for (; i + 4 <= n; i += 4) {
    int s0 = esrc[start + i + 0];
    int s1 = esrc[start + i + 1];
    int s2 = esrc[start + i + 2];
    int s3 = esrc[start + i + 3];
    float v0 = x[(size_t)s0 * CD_IN + c];
    float v1 = x[(size_t)s1 * CD_IN + c];
    float v2 = x[(size_t)s2 * CD_IN + c];
    float v3 = x[(size_t)s3 * CD_IN + c];
    acc += (v0 + v1) + (v2 + v3);
  }
  for (; i < n; ++i) acc += x[(size_t)esrc[start + i] * CD_IN + c];
  agg[(size_t)d * CD_IN + c] = acc / fmaxf((float)n, 1.0f);
}

// ---------------- gather-mean, 64 threads per dst (layer 2, width 64) ----------------
__global__ __launch_bounds__(256) void sage_gather2(
    const float* __restrict__ t2, const int* __restrict__ esrc,
    const int* __restrict__ R, const int* __restrict__ deg,
    float* __restrict__ agg) {
  int d = blockIdx.x * 4 + (threadIdx.x >> 6);
  int c = threadIdx.x & 63;
  if (d >= CN2) return;
  int start = R[d], n = deg[d];
  float acc = 0.0f;
  int i = 0;
  for (; i + 4 <= n; i += 4) {
    int s0 = esrc[start + i + 0];
    int s1 = esrc[start + i + 1];
    int s2 = esrc[start + i + 2];
    int s3 = esrc[start + i + 3];
    float v0 = t2[(size_t)s0 * CD_OUT + c];
    float v1 = t2[(size_t)s1 * CD_OUT + c];
    float v2 = t2[(size_t)s2 * CD_OUT + c];
    float v3 = t2[(size_t)s3 * CD_OUT + c];
    acc += (v0 + v1) + (v2 + v3);
  }
  for (; i < n; ++i) acc += t2[(size_t)esrc[start + i] * CD_OUT + c];
  agg[(size_t)d * CD_OUT + c] = acc / fmaxf((float)n, 1.0f);
}

// ---------------- gemm1: h1 = relu([agg | x] @ [W_l1|W_r1]^T + b) ----------------
// agg is already the mean. grid (ceil(N1/64), 2). block 256. 64x128 tile, KT=16, micro 4x8.
__global__ __launch_bounds__(256) void sage_gemm1(
    const float* __restrict__ agg, const float* __restrict__ x,
    const float* __restrict__ Wl, const float* __restrict__ Wr,
    const float* __restrict__ b, float* __restrict__ h1) {
  __shared__ float As[16][68];
  __shared__ float Ws[16][132];
  const int row0 = blockIdx.x * 64;
  const int col0 = blockIdx.y * 128;
  const int tid = threadIdx.x;
  const int tcol = tid & 15;
  const int trow = tid >> 4;

  const int arow = tid >> 2;
  const int ag = tid & 3;
  int grow = row0 + arow;
  int growc = grow < CN1 ? grow : CN1 - 1;

  const int wrow = tid >> 1;
  const int wg0 = (tid & 1) * 2;
  const int jglob = col0 + wrow;

  float acc[4][8] = {};

  for (int t = 0; t < 16; ++t) {
    const int kk = (t & 7) * 16;
    const float* Asrc = (t < 8) ? agg : x;
    const float* Wsrc = (t < 8) ? Wl : Wr;

    float4 av = reinterpret_cast<const float4*>(Asrc + (size_t)growc * CD_IN + kk)[ag];
    const float4* wp = reinterpret_cast<const float4*>(Wsrc + (size_t)jglob * CD_IN + kk);
    float4 w0 = wp[wg0];
    float4 w1 = wp[wg0 + 1];

    __syncthreads();
    As[ag * 4 + 0][arow] = av.x;
    As[ag * 4 + 1][arow] = av.y;
    As[ag * 4 + 2][arow] = av.z;
    As[ag * 4 + 3][arow] = av.w;
    Ws[wg0 * 4 + 0][wrow] = w0.x;
    Ws[wg0 * 4 + 1][wrow] = w0.y;
    Ws[wg0 * 4 + 2][wrow] = w0.z;
    Ws[wg0 * 4 + 3][wrow] = w0.w;
    Ws[wg0 * 4 + 4][wrow] = w1.x;
    Ws[wg0 * 4 + 5][wrow] = w1.y;
    Ws[wg0 * 4 + 6][wrow] = w1.z;
    Ws[wg0 * 4 + 7][wrow] = w1.w;
    __syncthreads();

#pragma unroll
    for (int k = 0; k < 16; ++k) {
      float4 a = *reinterpret_cast<const float4*>(&As[k][trow * 4]);
      float4 u0 = *reinterpret_cast<const float4*>(&Ws[k][tcol * 8]);
      float4 u1 = *reinterpret_cast<const float4*>(&Ws[k][tcol * 8 + 4]);
      float avv[4] = {a.x, a.y, a.z, a.w};
      float wvv[8] = {u0.x, u0.y, u0.z, u0.w, u1.x, u1.y, u1.z, u1.w};
#pragma unroll
      for (int r = 0; r < 4; ++r)
#pragma unroll
        for (int c = 0; c < 8; ++c)
          acc[r][c] = fmaf(avv[r], wvv[c], acc[r][c]);
    }
  }

  const int gc = col0 + tcol * 8;
  float4 b0 = *reinterpret_cast<const float4*>(b + gc);
  float4 b1 = *reinterpret_cast<const float4*>(b + gc + 4);
  float bv[8] = {b0.x, b0.y, b0.z, b0.w, b1.x, b1.y, b1.z, b1.w};
#pragma unroll
  for (int r = 0; r < 4; ++r) {
    int gr = row0 + trow * 4 + r;
    if (gr < CN1) {
      float4 o0, o1;
      o0.x = fmaxf(acc[r][0] + bv[0], 0.0f);
      o0.y = fmaxf(acc[r][1] + bv[1], 0.0f);
      o0.z = fmaxf(acc[r][2] + bv[2], 0.0f);
      o0.w = fmaxf(acc[r][3] + bv[3], 0.0f);
      o1.x = fmaxf(acc[r][4] + bv[4], 0.0f);
      o1.y = fmaxf(acc[r][5] + bv[5], 0.0f);
      o1.z = fmaxf(acc[r][6] + bv[6], 0.0f);
      o1.w = fmaxf(acc[r][7] + bv[7], 0.0f);
      float* op = &h1[(size_t)gr * CD_H + gc];
      *reinterpret_cast<float4*>(op) = o0;
      *reinterpret_cast<float4*>(op + 4) = o1;
    }
  }
}

// ---------------- gemm_nk64: out[M,64] = A[M,256] @ W[64,256]^T ----------------
__global__ __launch_bounds__(256) void sage_gemm_nk64(
    const float* __restrict__ A, const float* __restrict__ W,
    float* __restrict__ out, int M) {
  __shared__ float As[32][68];
  __shared__ float Ws[32][68];
  const int row0 = blockIdx.x * 64;
  const int tid = threadIdx.x;
  const int tc = tid & 15;
  const int tr = tid >> 4;

  float acc[4][4] = {};

  for (int t = 0; t < 8; ++t) {
    const int kk = t * 32;
    float4 va[2], vw[2];
    int rr[2], gg[2];
#pragma unroll
    for (int i = 0; i < 2; ++i) {
      int q = tid + 256 * i;
      int r = q >> 3;
      int g = q & 7;
      rr[i] = r; gg[i] = g;
      int gr = row0 + r;
      int grc = gr < M ? gr : M - 1;
      va[i] = reinterpret_cast<const float4*>(A + (size_t)grc * CD_H + kk)[g];
      vw[i] = reinterpret_cast<const float4*>(W + (size_t)r * CD_H + kk)[g];
    }
    __syncthreads();
#pragma unroll
    for (int i = 0; i < 2; ++i) {
      int r = rr[i], g = gg[i];
      As[g * 4 + 0][r] = va[i].x;
      As[g * 4 + 1][r] = va[i].y;
      As[g * 4 + 2][r] = va[i].z;
      As[g * 4 + 3][r] = va[i].w;
      Ws[g * 4 + 0][r] = vw[i].x;
      Ws[g * 4 + 1][r] = vw[i].y;
      Ws[g * 4 + 2][r] = vw[i].z;
      Ws[g * 4 + 3][r] = vw[i].w;
    }
    __syncthreads();

#pragma unroll
    for (int k = 0; k < 32; ++k) {
      float4 a = *reinterpret_cast<const float4*>(&As[k][tr * 4]);
      float4 w = *reinterpret_cast<const float4*>(&Ws[k][tc * 4]);
      float avv[4] = {a.x, a.y, a.z, a.w};
      float wvv[4] = {w.x, w.y, w.z, w.w};
#pragma unroll
      for (int r = 0; r < 4; ++r)
#pragma unroll
        for (int c = 0; c < 4; ++c)
          acc[r][c] = fmaf(avv[r], wvv[c], acc[r][c]);
    }
  }

#pragma unroll
  for (int r = 0; r < 4; ++r) {
    int gr = row0 + tr * 4 + r;
    if (gr < M) {
      float4 o;
      o.x = acc[r][0]; o.y = acc[r][1]; o.z = acc[r][2]; o.w = acc[r][3];
      *reinterpret_cast<float4*>(&out[(size_t)gr * CD_OUT + tc * 4]) = o;
    }
  }
}

// ---------------- finalize: out = log_softmax(out + agg2 + b2) ----------------
__global__ __launch_bounds__(256) void sage_finalize(
    const float* __restrict__ agg2, const float* __restrict__ b,
    float* __restrict__ out) {
  int row = blockIdx.x * 4 + (threadIdx.x >> 6);
  int lane = threadIdx.x & 63;
  if (row >= CN2) return;
  size_t o = (size_t)row * CD_OUT + lane;
  float v = out[o] + agg2[o] + b[lane];
  float m = v;
#pragma unroll
  for (int d = 32; d > 0; d >>= 1) m = fmaxf(m, __shfl_xor(m, d));
  float e = expf(v - m);
  float s = e;
#pragma unroll
  for (int d = 32; d > 0; d >>= 1) s += __shfl_xor(s, d);
  out[o] = v - m - logf(s);
}

extern "C" void kernel_launch(void* const* d_in, const int* in_sizes, int n_in,
                              void* d_out, int out_size, void* d_ws, size_t ws_size,
                              hipStream_t stream) {
  const float* x    = (const float*)d_in[0];
  const int* src1   = (const int*)d_in[1];
  const int* dst1   = (const int*)d_in[2];
  const int* src2   = (const int*)d_in[3];
  const int* dst2   = (const int*)d_in[4];
  const float* W_l1 = (const float*)d_in[5];
  const float* b_l1 = (const float*)d_in[6];
  const float* W_r1 = (const float*)d_in[7];
  const float* W_l2 = (const float*)d_in[8];
  const float* b_l2 = (const float*)d_in[9];
  const float* W_r2 = (const float*)d_in[10];
  float* out = (float*)d_out;
  float* ws = (float*)d_ws;

  // ---- workspace layout (float offsets), total 38.4M floats = 153.6 MB ----
  // Region A [0, 12.8M): agg1 (N1*128).
  //   After gemm1 consumes agg1, region A is re-used:
  //     t2   = A[0, 6.4M)            (N1*64)
  //     agg2 = A[6.4M, 7.68M)        (N2*64)
  //     layer-2 CSR ints at A+7.68M: deg2,R2,cur2[20000 ea], part2[256], esrc2[320000]
  // Region H [12.8M, 38.4M): h1 (N1*256).
  //   Before gemm1 writes h1, its head holds layer-1 CSR ints:
  //     deg1,R1,cur1[100000 ea], part1[256], esrc1[1600000]  (~7.6 MB)
  float* agg1 = ws;
  float* t2   = ws;                                   // alias (after gemm1)
  float* agg2 = ws + (size_t)CN1 * CD_OUT;            // alias (after gemm1)
  int*   l2i  = (int*)(ws + (size_t)CN1 * CD_OUT + (size_t)CN2 * CD_OUT);
  int* deg2 = l2i;
  int* R2   = deg2 + CN2;
  int* cur2 = R2 + CN2;
  int* part2= cur2 + CN2;
  int* esrc2= part2 + 256;

  float* h1 = ws + (size_t)CN1 * CD_IN;
  int* l1i  = (int*)h1;                               // alias (before gemm1)
  int* deg1 = l1i;
  int* R1   = deg1 + CN1;
  int* cur1 = R1 + CN1;
  int* part1= cur1 + CN1;
  int* esrc1= part1 + 256;

  size_t need_bytes = ((size_t)CN1 * CD_IN + (size_t)CN1 * CD_H) * 4;
  if (ws_size < need_bytes) return;

  const int B1 = (CN1 + 511) / 512;   // 196
  const int B2 = (CN2 + 511) / 512;   // 40

  // ---- layer 1 CSR + gather ----
  hipMemsetAsync(deg1, 0, CN1 * sizeof(int), stream);
  sage_hist<<<(CE1 + 255) / 256, 256, 0, stream>>>(dst1, deg1, CE1);
  sage_scan_local<<<B1, 256, 0, stream>>>(deg1, R1, part1, CN1);
  sage_scan_part<<<1, 1, 0, stream>>>(part1, B1);
  sage_addback<<<(CN1 + 255) / 256, 256, 0, stream>>>(R1, cur1, part1, CN1);
  sage_place<<<(CE1 + 255) / 256, 256, 0, stream>>>(src1, dst1, cur1, esrc1, CE1);
  sage_gather1<<<(CN1 + 1) / 2, 256, 0, stream>>>(x, esrc1, R1, deg1, agg1);

  // ---- layer 1 GEMM (writes h1; layer-1 ints now dead) ----
  sage_gemm1<<<dim3((CN1 + 63) / 64, 2), 256, 0, stream>>>(
      agg1, x, W_l1, W_r1, b_l1, h1);

  // ---- premultiply t2 = h1 @ W_l2^T (overwrites dead agg1) ----
  sage_gemm_nk64<<<(CN1 + 63) / 64, 256, 0, stream>>>(h1, W_l2, t2, CN1);

  // ---- layer 2 CSR + gather (ints live in dead upper agg1 region) ----
  hipMemsetAsync(deg2, 0, CN2 * sizeof(int), stream);
  sage_hist<<<(CE2 + 255) / 256, 256, 0, stream>>>(dst2, deg2, CE2);
  sage_scan_local<<<B2, 256, 0, stream>>>(deg2, R2, part2, CN2);
  sage_scan_part<<<1, 1, 0, stream>>>(part2, B2);
  sage_addback<<<(CN2 + 255) / 256, 256, 0, stream>>>(R2, cur2, part2, CN2);
  sage_place<<<(CE2 + 255) / 256, 256, 0, stream>>>(src2, dst2, cur2, esrc2, CE2);
  sage_gather2<<<(CN2 + 3) / 4, 256, 0, stream>>>(t2, esrc2, R2, deg2, agg2);

  // ---- out = log_softmax(h1[:N2] @ W_r2^T + agg2 + b2) ----
  sage_gemm_nk64<<<(CN2 + 63) / 64, 256, 0, stream>>>(h1, W_r2, out, CN2);
  sage_finalize<<<(CN2 + 3) / 4, 256, 0, stream>>>(agg2, b_l2, out);
}

// Round 4
// 546.979 us; speedup vs baseline: 6.0491x; 1.2203x over previous
//
#include <hip/hip_runtime.h>
#include <stdint.h>

// SAGE_876173328847: 2-layer bipartite SAGEConv (mean agg) + log_softmax.
// N0=200000, N1=100000, N2=20000, E1=1.6M, E2=320K, D_IN=128, D_H=256, D_OUT=64.
//
// R1: atomic scatter -> CSR build + gather (3309 -> 667 us).
// R2: bf16 heavy path + MFMA GEMMs (NaN: staged only half of each BK=64 LDS tile).
// R3: fix staging counts (A: 4 int4/thread, W: 2 int4/thread).

#define CN0 200000
#define CN1 100000
#define CN2 20000
#define CE1 1600000
#define CE2 320000
#define CD_IN 128
#define CD_H 256
#define CD_OUT 64

typedef __bf16 bf16x8 __attribute__((ext_vector_type(8)));
typedef float f32x4 __attribute__((ext_vector_type(4)));
typedef uint16_t u16x4 __attribute__((ext_vector_type(4)));

__device__ inline uint16_t f2bf(float f) {
  uint32_t u = __float_as_uint(f);
  return (uint16_t)((u + 0x7fffu + ((u >> 16) & 1u)) >> 16);
}

// ---------------- dtype converts ----------------
__global__ __launch_bounds__(256) void cvt_f32_bf16_v4(
    const float* __restrict__ in, uint16_t* __restrict__ out, int n4) {
  int i = blockIdx.x * 256 + threadIdx.x;
  if (i >= n4) return;
  float4 v = reinterpret_cast<const float4*>(in)[i];
  u16x4 o = {f2bf(v.x), f2bf(v.y), f2bf(v.z), f2bf(v.w)};
  reinterpret_cast<u16x4*>(out)[i] = o;
}

__global__ __launch_bounds__(256) void cvt_wcat(
    const float* __restrict__ Wl, const float* __restrict__ Wr,
    uint16_t* __restrict__ out) {
  int i = blockIdx.x * 256 + threadIdx.x;  // 65536 total
  int j = i >> 8, k = i & 255;
  float v = (k < 128) ? Wl[j * 128 + k] : Wr[j * 128 + (k - 128)];
  out[i] = f2bf(v);
}

__global__ __launch_bounds__(256) void cvt_small(
    const float* __restrict__ in, uint16_t* __restrict__ out, int n) {
  int i = blockIdx.x * 256 + threadIdx.x;
  if (i < n) out[i] = f2bf(in[i]);
}

// ---------------- CSR build ----------------
__global__ __launch_bounds__(256) void sage_hist(
    const int* __restrict__ dst, int* __restrict__ deg, int E) {
  int e = blockIdx.x * 256 + threadIdx.x;
  if (e < E) atomicAdd(&deg[dst[e]], 1);
}

__global__ __launch_bounds__(256) void sage_scan_local(
    const int* __restrict__ deg, int* __restrict__ R, int* __restrict__ part, int N) {
  __shared__ int sm[256];
  int t = threadIdx.x;
  int base = blockIdx.x * 512;
  int i0 = base + 2 * t, i1 = base + 2 * t + 1;
  int a = (i0 < N) ? deg[i0] : 0;
  int b = (i1 < N) ? deg[i1] : 0;
  int s = a + b;
  sm[t] = s;
  __syncthreads();
#pragma unroll
  for (int off = 1; off < 256; off <<= 1) {
    int v = (t >= off) ? sm[t - off] : 0;
    __syncthreads();
    sm[t] += v;
    __syncthreads();
  }
  int excl = sm[t] - s;
  if (i0 < N) R[i0] = excl;
  if (i1 < N) R[i1] = excl + a;
  if (t == 255) part[blockIdx.x] = sm[255];
}

// parallel exclusive scan of part[0..B), B <= 256, single block of 256
__global__ __launch_bounds__(256) void sage_scan_part(int* __restrict__ part, int B) {
  __shared__ int sm[256];
  int t = threadIdx.x;
  int v = (t < B) ? part[t] : 0;
  sm[t] = v;
  __syncthreads();
#pragma unroll
  for (int off = 1; off < 256; off <<= 1) {
    int u = (t >= off) ? sm[t - off] : 0;
    __syncthreads();
    sm[t] += u;
    __syncthreads();
  }
  if (t < B) part[t] = sm[t] - v;
}

__global__ __launch_bounds__(256) void sage_addback(
    int* __restrict__ R, int* __restrict__ cur, const int* __restrict__ part, int N) {
  int i = blockIdx.x * 256 + threadIdx.x;
  if (i < N) { int v = R[i] + part[i >> 9]; R[i] = v; cur[i] = v; }
}

__global__ __launch_bounds__(256) void sage_place(
    const int* __restrict__ src, const int* __restrict__ dst,
    int* __restrict__ cur, int* __restrict__ esrc, int E) {
  int e = blockIdx.x * 256 + threadIdx.x;
  if (e < E) {
    int p = atomicAdd(&cur[dst[e]], 1);
    esrc[p] = src[e];
  }
}

// ---------------- gather-mean (bf16 in), layer 1: 64 lanes/dst, 2 cols/lane ----
__global__ __launch_bounds__(256) void sage_gather1(
    const uint16_t* __restrict__ xbf, const int* __restrict__ esrc,
    const int* __restrict__ R, const int* __restrict__ deg,
    uint16_t* __restrict__ agg) {
  int d = blockIdx.x * 4 + (threadIdx.x >> 6);
  int c = threadIdx.x & 63;
  if (d >= CN1) return;
  int start = R[d], n = deg[d];
  const uint32_t* xw = reinterpret_cast<const uint32_t*>(xbf);
  float a0 = 0.f, a1 = 0.f;
  int i = 0;
  for (; i + 4 <= n; i += 4) {
    int s0 = esrc[start + i + 0];
    int s1 = esrc[start + i + 1];
    int s2 = esrc[start + i + 2];
    int s3 = esrc[start + i + 3];
    uint32_t v0 = xw[(size_t)s0 * 64 + c];
    uint32_t v1 = xw[(size_t)s1 * 64 + c];
    uint32_t v2 = xw[(size_t)s2 * 64 + c];
    uint32_t v3 = xw[(size_t)s3 * 64 + c];
    a0 += __uint_as_float(v0 << 16) + __uint_as_float(v1 << 16) +
          __uint_as_float(v2 << 16) + __uint_as_float(v3 << 16);
    a1 += __uint_as_float(v0 & 0xffff0000u) + __uint_as_float(v1 & 0xffff0000u) +
          __uint_as_float(v2 & 0xffff0000u) + __uint_as_float(v3 & 0xffff0000u);
  }
  for (; i < n; ++i) {
    uint32_t v = xw[(size_t)esrc[start + i] * 64 + c];
    a0 += __uint_as_float(v << 16);
    a1 += __uint_as_float(v & 0xffff0000u);
  }
  float inv = 1.0f / fmaxf((float)n, 1.0f);
  a0 *= inv; a1 *= inv;
  uint32_t packed = (uint32_t)f2bf(a0) | ((uint32_t)f2bf(a1) << 16);
  reinterpret_cast<uint32_t*>(agg)[(size_t)d * 64 + c] = packed;
}

// ---------------- gather-mean (bf16 in), layer 2: 32 lanes/dst, f32 out ----
__global__ __launch_bounds__(256) void sage_gather2(
    const uint16_t* __restrict__ t2, const int* __restrict__ esrc,
    const int* __restrict__ R, const int* __restrict__ deg,
    float* __restrict__ agg) {
  int d = blockIdx.x * 8 + (threadIdx.x >> 5);
  int c = threadIdx.x & 31;
  if (d >= CN2) return;
  int start = R[d], n = deg[d];
  const uint32_t* tw = reinterpret_cast<const uint32_t*>(t2);
  float a0 = 0.f, a1 = 0.f;
  int i = 0;
  for (; i + 4 <= n; i += 4) {
    int s0 = esrc[start + i + 0];
    int s1 = esrc[start + i + 1];
    int s2 = esrc[start + i + 2];
    int s3 = esrc[start + i + 3];
    uint32_t v0 = tw[(size_t)s0 * 32 + c];
    uint32_t v1 = tw[(size_t)s1 * 32 + c];
    uint32_t v2 = tw[(size_t)s2 * 32 + c];
    uint32_t v3 = tw[(size_t)s3 * 32 + c];
    a0 += __uint_as_float(v0 << 16) + __uint_as_float(v1 << 16) +
          __uint_as_float(v2 << 16) + __uint_as_float(v3 << 16);
    a1 += __uint_as_float(v0 & 0xffff0000u) + __uint_as_float(v1 & 0xffff0000u) +
          __uint_as_float(v2 & 0xffff0000u) + __uint_as_float(v3 & 0xffff0000u);
  }
  for (; i < n; ++i) {
    uint32_t v = tw[(size_t)esrc[start + i] * 32 + c];
    a0 += __uint_as_float(v << 16);
    a1 += __uint_as_float(v & 0xffff0000u);
  }
  float inv = 1.0f / fmaxf((float)n, 1.0f);
  float2 o = {a0 * inv, a1 * inv};
  reinterpret_cast<float2*>(agg)[(size_t)d * 32 + c] = o;
}

// ---------------- MFMA GEMM: out[M,N] = A[M,256] @ W[N,256]^T (+bias, relu) ----
// Block tile 128(M) x 64(N), BK=64, 4 waves (wave w: rows w*32..w*32+31).
// K fixed at 256. A is split at `ksplit` between A0 and A1 (both row-stride lda).
// grid = (ceil(M/128), N/64).
template <bool RELU_BIAS, bool OUT_BF16>
__global__ __launch_bounds__(256) void sage_mfma_gemm(
    const uint16_t* __restrict__ A0, const uint16_t* __restrict__ A1,
    int lda, int ksplit, const uint16_t* __restrict__ W,
    const float* __restrict__ bias, void* __restrict__ outp, int ldo, int M) {
  __shared__ uint16_t As[128 * 72];  // 72 = 64 + 8 pad
  __shared__ uint16_t Ws[64 * 72];
  const int tid = threadIdx.x;
  const int wid = tid >> 6;
  const int lane = tid & 63;
  const int lr = lane >> 4;   // k-group (A/B) / row-group (C)
  const int lc = lane & 15;   // fragment row (A) / col (B, C)
  const int row0 = blockIdx.x * 128;
  const int col0 = blockIdx.y * 64;

  f32x4 acc[2][4];
#pragma unroll
  for (int m = 0; m < 2; ++m)
#pragma unroll
    for (int n = 0; n < 4; ++n) acc[m][n] = (f32x4)0.0f;

  for (int t = 0; t < 4; ++t) {
    const int k0 = t * 64;
    const uint16_t* Asrc;
    int koff;
    if (k0 < ksplit) { Asrc = A0; koff = k0; }
    else             { Asrc = A1; koff = k0 - ksplit; }

    // A tile: 128 rows x 64 k = 1024 int4 -> 4 per thread
    int4 av[4];
#pragma unroll
    for (int i = 0; i < 4; ++i) {
      int q = tid + 256 * i;            // 0..1023
      int r = q >> 3, c = q & 7;        // r 0..127, c 0..7
      int rg = row0 + r;
      rg = rg < M ? rg : M - 1;
      av[i] = *reinterpret_cast<const int4*>(Asrc + (size_t)rg * lda + koff + c * 8);
    }
    // W tile: 64 rows x 64 k = 512 int4 -> 2 per thread
    int4 wv[2];
#pragma unroll
    for (int i = 0; i < 2; ++i) {
      int q = tid + 256 * i;            // 0..511
      int r = q >> 3, c = q & 7;        // r 0..63
      wv[i] = *reinterpret_cast<const int4*>(W + (size_t)(col0 + r) * 256 + k0 + c * 8);
    }
    __syncthreads();
#pragma unroll
    for (int i = 0; i < 4; ++i) {
      int q = tid + 256 * i;
      int r = q >> 3, c = q & 7;
      *reinterpret_cast<int4*>(&As[r * 72 + c * 8]) = av[i];
    }
#pragma unroll
    for (int i = 0; i < 2; ++i) {
      int q = tid + 256 * i;
      int r = q >> 3, c = q & 7;
      *reinterpret_cast<int4*>(&Ws[r * 72 + c * 8]) = wv[i];
    }
    __syncthreads();

#pragma unroll
    for (int ks = 0; ks < 2; ++ks) {
      const int kb = ks * 32 + lr * 8;
      bf16x8 af[2], bfv[4];
#pragma unroll
      for (int m = 0; m < 2; ++m)
        af[m] = *reinterpret_cast<const bf16x8*>(&As[(wid * 32 + m * 16 + lc) * 72 + kb]);
#pragma unroll
      for (int n = 0; n < 4; ++n)
        bfv[n] = *reinterpret_cast<const bf16x8*>(&Ws[(n * 16 + lc) * 72 + kb]);
#pragma unroll
      for (int m = 0; m < 2; ++m)
#pragma unroll
        for (int n = 0; n < 4; ++n)
          acc[m][n] = __builtin_amdgcn_mfma_f32_16x16x32_bf16(af[m], bfv[n], acc[m][n], 0, 0, 0);
    }
  }

  // epilogue: C row = (lane>>4)*4 + reg, col = lane&15  (m89-verified layout)
  float bb[4];
  if (RELU_BIAS) {
#pragma unroll
    for (int n = 0; n < 4; ++n) bb[n] = bias[col0 + n * 16 + lc];
  }
#pragma unroll
  for (int m = 0; m < 2; ++m) {
#pragma unroll
    for (int i = 0; i < 4; ++i) {
      int rg = row0 + wid * 32 + m * 16 + lr * 4 + i;
      if (rg < M) {
#pragma unroll
        for (int n = 0; n < 4; ++n) {
          float v = acc[m][n][i];
          if (RELU_BIAS) v = fmaxf(v + bb[n], 0.0f);
          int cg = col0 + n * 16 + lc;
          if (OUT_BF16)
            reinterpret_cast<uint16_t*>(outp)[(size_t)rg * ldo + cg] = f2bf(v);
          else
            reinterpret_cast<float*>(outp)[(size_t)rg * ldo + cg] = v;
        }
      }
    }
  }
}

// ---------------- finalize: out = log_softmax(out + agg2 + b2) ----------------
__global__ __launch_bounds__(256) void sage_finalize(
    const float* __restrict__ agg2, const float* __restrict__ b,
    float* __restrict__ out) {
  int row = blockIdx.x * 4 + (threadIdx.x >> 6);
  int lane = threadIdx.x & 63;
  if (row >= CN2) return;
  size_t o = (size_t)row * CD_OUT + lane;
  float v = out[o] + agg2[o] + b[lane];
  float m = v;
#pragma unroll
  for (int d = 32; d > 0; d >>= 1) m = fmaxf(m, __shfl_xor(m, d));
  float e = expf(v - m);
  float s = e;
#pragma unroll
  for (int d = 32; d > 0; d >>= 1) s += __shfl_xor(s, d);
  out[o] = v - m - logf(s);
}

extern "C" void kernel_launch(void* const* d_in, const int* in_sizes, int n_in,
                              void* d_out, int out_size, void* d_ws, size_t ws_size,
                              hipStream_t stream) {
  const float* x    = (const float*)d_in[0];
  const int* src1   = (const int*)d_in[1];
  const int* dst1   = (const int*)d_in[2];
  const int* src2   = (const int*)d_in[3];
  const int* dst2   = (const int*)d_in[4];
  const float* W_l1 = (const float*)d_in[5];
  const float* b_l1 = (const float*)d_in[6];
  const float* W_r1 = (const float*)d_in[7];
  const float* W_l2 = (const float*)d_in[8];
  const float* b_l2 = (const float*)d_in[9];
  const float* W_r2 = (const float*)d_in[10];
  float* out = (float*)d_out;
  char* base = (char*)d_ws;

  // ---- workspace layout (bytes), total 135,797,632 ----
  // [0, 51.2M)        x_bf       [N0][128] bf16
  // [51.2M, 102.4M)   h1_bf      [N1][256] bf16
  // [102.4M, 128.0M)  R-region (25.6M):
  //     phase A: agg1_bf [N1][128] bf16 (dead after gemm1)
  //     phase B: t2_bf [N1][64] bf16 (12.8M) | agg2 [N2][64] f32 (5.12M) | CSR2 ints
  // [128.0M, 135.6M)  CSR1 ints: deg1,R1,cur1 (3x400K), part1(1K), esrc1(6.4M)
  // [135.6M, 135.8M)  bf16 weights: Wcat[256][256], W2l[64][256], W2r[64][256]
  uint16_t* x_bf  = (uint16_t*)base;
  uint16_t* h1_bf = (uint16_t*)(base + 51200000);
  char* Rreg = base + 102400000;
  uint16_t* agg_bf = (uint16_t*)Rreg;
  uint16_t* t2_bf  = (uint16_t*)Rreg;
  float* agg2 = (float*)(Rreg + 12800000);
  int* deg2 = (int*)(Rreg + 17920000);
  int* R2   = deg2 + CN2;
  int* cur2 = R2 + CN2;
  int* part2 = cur2 + CN2;
  int* esrc2 = part2 + 256;
  char* csr1 = base + 128000000;
  int* deg1 = (int*)csr1;
  int* R1   = deg1 + CN1;
  int* cur1 = R1 + CN1;
  int* part1 = cur1 + CN1;
  int* esrc1 = part1 + 256;
  uint16_t* wcat = (uint16_t*)(base + 135601024);
  uint16_t* w2l  = wcat + 65536;
  uint16_t* w2r  = w2l + 16384;

  if (ws_size < 135797632u) return;

  const int B1 = (CN1 + 511) / 512;  // 196
  const int B2 = (CN2 + 511) / 512;  // 40
  const int NOSPLIT = 1 << 30;

  // ---- converts ----
  cvt_f32_bf16_v4<<<(CN0 * CD_IN / 4 + 255) / 256, 256, 0, stream>>>(x, x_bf, CN0 * CD_IN / 4);
  cvt_wcat<<<256, 256, 0, stream>>>(W_l1, W_r1, wcat);
  cvt_small<<<64, 256, 0, stream>>>(W_l2, w2l, CD_OUT * CD_H);
  cvt_small<<<64, 256, 0, stream>>>(W_r2, w2r, CD_OUT * CD_H);

  // ---- layer 1 CSR + gather ----
  hipMemsetAsync(deg1, 0, CN1 * sizeof(int), stream);
  sage_hist<<<(CE1 + 255) / 256, 256, 0, stream>>>(dst1, deg1, CE1);
  sage_scan_local<<<B1, 256, 0, stream>>>(deg1, R1, part1, CN1);
  sage_scan_part<<<1, 256, 0, stream>>>(part1, B1);
  sage_addback<<<(CN1 + 255) / 256, 256, 0, stream>>>(R1, cur1, part1, CN1);
  sage_place<<<(CE1 + 255) / 256, 256, 0, stream>>>(src1, dst1, cur1, esrc1, CE1);
  sage_gather1<<<(CN1 + 3) / 4, 256, 0, stream>>>(x_bf, esrc1, R1, deg1, agg_bf);

  // ---- h1 = relu([agg1 | x] @ Wcat^T + b1), bf16 out ----
  sage_mfma_gemm<true, true><<<dim3((CN1 + 127) / 128, 4), 256, 0, stream>>>(
      agg_bf, x_bf, CD_IN, CD_IN, wcat, b_l1, h1_bf, CD_H, CN1);

  // ---- t2 = h1 @ W_l2^T, bf16 out (overwrites dead agg1) ----
  sage_mfma_gemm<false, true><<<dim3((CN1 + 127) / 128, 1), 256, 0, stream>>>(
      h1_bf, h1_bf, CD_H, NOSPLIT, w2l, nullptr, t2_bf, CD_OUT, CN1);

  // ---- layer 2 CSR + gather ----
  hipMemsetAsync(deg2, 0, CN2 * sizeof(int), stream);
  sage_hist<<<(CE2 + 255) / 256, 256, 0, stream>>>(dst2, deg2, CE2);
  sage_scan_local<<<B2, 256, 0, stream>>>(deg2, R2, part2, CN2);
  sage_scan_part<<<1, 256, 0, stream>>>(part2, B2);
  sage_addback<<<(CN2 + 255) / 256, 256, 0, stream>>>(R2, cur2, part2, CN2);
  sage_place<<<(CE2 + 255) / 256, 256, 0, stream>>>(src2, dst2, cur2, esrc2, CE2);
  sage_gather2<<<(CN2 + 7) / 8, 256, 0, stream>>>(t2_bf, esrc2, R2, deg2, agg2);

  // ---- out = log_softmax(h1[:N2] @ W_r2^T + agg2 + b2) ----
  sage_mfma_gemm<false, false><<<dim3((CN2 + 127) / 128, 1), 256, 0, stream>>>(
      h1_bf, h1_bf, CD_H, NOSPLIT, w2r, nullptr, out, CD_OUT, CN2);
  sage_finalize<<<(CN2 + 3) / 4, 256, 0, stream>>>(agg2, b_l2, out);
}

// Round 5
// 472.448 us; speedup vs baseline: 7.0034x; 1.1578x over previous
//
#include <hip/hip_runtime.h>
#include <stdint.h>

// SAGE_876173328847: 2-layer bipartite SAGEConv (mean agg) + log_softmax.
// N0=200000, N1=100000, N2=20000, E1=1.6M, E2=320K, D_IN=128, D_H=256, D_OUT=64.
//
// R1: atomic scatter -> CSR build + gather (3309 -> 667 us).
// R2/R3: bf16 heavy path + MFMA GEMMs (667 -> 547 us).
// R4: gemm1 was HBM-bound (578 MB vs 102 MB logical: 4x A re-read from col-split
//     grid + 6.8x h1 write amplification). Fuse gemm1+t2gemm+outgemm into one
//     mega-kernel: h1 tile lives only in LDS, never written to HBM.

#define CN0 200000
#define CN1 100000
#define CN2 20000
#define CE1 1600000
#define CE2 320000
#define CD_IN 128
#define CD_H 256
#define CD_OUT 64

typedef __bf16 bf16x8 __attribute__((ext_vector_type(8)));
typedef float f32x4 __attribute__((ext_vector_type(4)));
typedef uint16_t u16x4 __attribute__((ext_vector_type(4)));

__device__ inline uint16_t f2bf(float f) {
  uint32_t u = __float_as_uint(f);
  return (uint16_t)((u + 0x7fffu + ((u >> 16) & 1u)) >> 16);
}

// ---------------- dtype converts ----------------
__global__ __launch_bounds__(256) void cvt_f32_bf16_v4(
    const float* __restrict__ in, uint16_t* __restrict__ out, int n4) {
  int i = blockIdx.x * 256 + threadIdx.x;
  if (i >= n4) return;
  float4 v = reinterpret_cast<const float4*>(in)[i];
  u16x4 o = {f2bf(v.x), f2bf(v.y), f2bf(v.z), f2bf(v.w)};
  reinterpret_cast<u16x4*>(out)[i] = o;
}

__global__ __launch_bounds__(256) void cvt_wcat(
    const float* __restrict__ Wl, const float* __restrict__ Wr,
    uint16_t* __restrict__ out) {
  int i = blockIdx.x * 256 + threadIdx.x;  // 65536 total
  int j = i >> 8, k = i & 255;
  float v = (k < 128) ? Wl[j * 128 + k] : Wr[j * 128 + (k - 128)];
  out[i] = f2bf(v);
}

__global__ __launch_bounds__(256) void cvt_small(
    const float* __restrict__ in, uint16_t* __restrict__ out, int n) {
  int i = blockIdx.x * 256 + threadIdx.x;
  if (i < n) out[i] = f2bf(in[i]);
}

// ---------------- CSR build ----------------
__global__ __launch_bounds__(256) void sage_hist(
    const int* __restrict__ dst, int* __restrict__ deg, int E) {
  int e = blockIdx.x * 256 + threadIdx.x;
  if (e < E) atomicAdd(&deg[dst[e]], 1);
}

__global__ __launch_bounds__(256) void sage_scan_local(
    const int* __restrict__ deg, int* __restrict__ R, int* __restrict__ part, int N) {
  __shared__ int sm[256];
  int t = threadIdx.x;
  int base = blockIdx.x * 512;
  int i0 = base + 2 * t, i1 = base + 2 * t + 1;
  int a = (i0 < N) ? deg[i0] : 0;
  int b = (i1 < N) ? deg[i1] : 0;
  int s = a + b;
  sm[t] = s;
  __syncthreads();
#pragma unroll
  for (int off = 1; off < 256; off <<= 1) {
    int v = (t >= off) ? sm[t - off] : 0;
    __syncthreads();
    sm[t] += v;
    __syncthreads();
  }
  int excl = sm[t] - s;
  if (i0 < N) R[i0] = excl;
  if (i1 < N) R[i1] = excl + a;
  if (t == 255) part[blockIdx.x] = sm[255];
}

__global__ __launch_bounds__(256) void sage_scan_part(int* __restrict__ part, int B) {
  __shared__ int sm[256];
  int t = threadIdx.x;
  int v = (t < B) ? part[t] : 0;
  sm[t] = v;
  __syncthreads();
#pragma unroll
  for (int off = 1; off < 256; off <<= 1) {
    int u = (t >= off) ? sm[t - off] : 0;
    __syncthreads();
    sm[t] += u;
    __syncthreads();
  }
  if (t < B) part[t] = sm[t] - v;
}

__global__ __launch_bounds__(256) void sage_addback(
    int* __restrict__ R, int* __restrict__ cur, const int* __restrict__ part, int N) {
  int i = blockIdx.x * 256 + threadIdx.x;
  if (i < N) { int v = R[i] + part[i >> 9]; R[i] = v; cur[i] = v; }
}

__global__ __launch_bounds__(256) void sage_place(
    const int* __restrict__ src, const int* __restrict__ dst,
    int* __restrict__ cur, int* __restrict__ esrc, int E) {
  int e = blockIdx.x * 256 + threadIdx.x;
  if (e < E) {
    int p = atomicAdd(&cur[dst[e]], 1);
    esrc[p] = src[e];
  }
}

// ---------------- gather-mean (bf16 in), layer 1: 64 lanes/dst ----------------
__global__ __launch_bounds__(256) void sage_gather1(
    const uint16_t* __restrict__ xbf, const int* __restrict__ esrc,
    const int* __restrict__ R, const int* __restrict__ deg,
    uint16_t* __restrict__ agg) {
  int d = blockIdx.x * 4 + (threadIdx.x >> 6);
  int c = threadIdx.x & 63;
  if (d >= CN1) return;
  int start = R[d], n = deg[d];
  const uint32_t* xw = reinterpret_cast<const uint32_t*>(xbf);
  float a0 = 0.f, a1 = 0.f;
  int i = 0;
  for (; i + 4 <= n; i += 4) {
    int s0 = esrc[start + i + 0];
    int s1 = esrc[start + i + 1];
    int s2 = esrc[start + i + 2];
    int s3 = esrc[start + i + 3];
    uint32_t v0 = xw[(size_t)s0 * 64 + c];
    uint32_t v1 = xw[(size_t)s1 * 64 + c];
    uint32_t v2 = xw[(size_t)s2 * 64 + c];
    uint32_t v3 = xw[(size_t)s3 * 64 + c];
    a0 += __uint_as_float(v0 << 16) + __uint_as_float(v1 << 16) +
          __uint_as_float(v2 << 16) + __uint_as_float(v3 << 16);
    a1 += __uint_as_float(v0 & 0xffff0000u) + __uint_as_float(v1 & 0xffff0000u) +
          __uint_as_float(v2 & 0xffff0000u) + __uint_as_float(v3 & 0xffff0000u);
  }
  for (; i < n; ++i) {
    uint32_t v = xw[(size_t)esrc[start + i] * 64 + c];
    a0 += __uint_as_float(v << 16);
    a1 += __uint_as_float(v & 0xffff0000u);
  }
  float inv = 1.0f / fmaxf((float)n, 1.0f);
  a0 *= inv; a1 *= inv;
  uint32_t packed = (uint32_t)f2bf(a0) | ((uint32_t)f2bf(a1) << 16);
  reinterpret_cast<uint32_t*>(agg)[(size_t)d * 64 + c] = packed;
}

// ---------------- gather-mean (bf16 in), layer 2: 32 lanes/dst, f32 out ----
__global__ __launch_bounds__(256) void sage_gather2(
    const uint16_t* __restrict__ t2, const int* __restrict__ esrc,
    const int* __restrict__ R, const int* __restrict__ deg,
    float* __restrict__ agg) {
  int d = blockIdx.x * 8 + (threadIdx.x >> 5);
  int c = threadIdx.x & 31;
  if (d >= CN2) return;
  int start = R[d], n = deg[d];
  const uint32_t* tw = reinterpret_cast<const uint32_t*>(t2);
  float a0 = 0.f, a1 = 0.f;
  int i = 0;
  for (; i + 4 <= n; i += 4) {
    int s0 = esrc[start + i + 0];
    int s1 = esrc[start + i + 1];
    int s2 = esrc[start + i + 2];
    int s3 = esrc[start + i + 3];
    uint32_t v0 = tw[(size_t)s0 * 32 + c];
    uint32_t v1 = tw[(size_t)s1 * 32 + c];
    uint32_t v2 = tw[(size_t)s2 * 32 + c];
    uint32_t v3 = tw[(size_t)s3 * 32 + c];
    a0 += __uint_as_float(v0 << 16) + __uint_as_float(v1 << 16) +
          __uint_as_float(v2 << 16) + __uint_as_float(v3 << 16);
    a1 += __uint_as_float(v0 & 0xffff0000u) + __uint_as_float(v1 & 0xffff0000u) +
          __uint_as_float(v2 & 0xffff0000u) + __uint_as_float(v3 & 0xffff0000u);
  }
  for (; i < n; ++i) {
    uint32_t v = tw[(size_t)esrc[start + i] * 32 + c];
    a0 += __uint_as_float(v << 16);
    a1 += __uint_as_float(v & 0xffff0000u);
  }
  float inv = 1.0f / fmaxf((float)n, 1.0f);
  float2 o = {a0 * inv, a1 * inv};
  reinterpret_cast<float2*>(agg)[(size_t)d * 32 + c] = o;
}

// ---------------- MEGA kernel ----------------
// Per 64-row block (grid ceil(N1/64), 256 thr = 4 waves; wave w owns rows w*16..w*16+15):
//   phase 1: h1_lds[64][256] = relu([agg|x] @ Wcat^T + b1)   (bf16, LDS only)
//   phase 2: t2[row]  = h1 @ W2cat[0:64]^T   (bf16 -> HBM)
//            out[row] = h1 @ W2cat[64:128]^T (f32 -> HBM, rows < N2 only)
// LDS: As 64x72 | Ws 256x72 (phase2: W2s 128x72 aliases) | h1s 64x264 = 79872 B.
__global__ __launch_bounds__(256) void sage_mega(
    const uint16_t* __restrict__ agg, const uint16_t* __restrict__ xbf,
    const uint16_t* __restrict__ wcat, const uint16_t* __restrict__ w2cat,
    const float* __restrict__ bias, uint16_t* __restrict__ t2,
    float* __restrict__ outp) {
  __shared__ uint16_t lds[39936];
  uint16_t* As  = lds;            // [64][72]
  uint16_t* Ws  = lds + 4608;     // [256][72]  (phase 2: W2s [128][72])
  uint16_t* h1s = lds + 23040;    // [64][264]

  const int tid = threadIdx.x;
  const int w = tid >> 6;
  const int lane = tid & 63;
  const int lr = lane >> 4;   // k-group (inputs) / row-group (C)
  const int lc = lane & 15;   // A-row / B-col / C-col
  const int row0 = blockIdx.x * 64;

  // ---- phase 1: h1 tile = relu([agg|x] @ Wcat^T + b) ----
  f32x4 acc1[16];
#pragma unroll
  for (int n = 0; n < 16; ++n) acc1[n] = (f32x4)0.0f;

  for (int t = 0; t < 4; ++t) {
    const int k0 = t * 64;
    const uint16_t* Asrc = (t < 2) ? agg : xbf;
    const int koff = (t < 2) ? k0 : k0 - 128;

    // A tile: 64 rows x 64 k = 512 int4 -> 2/thread
    int4 av[2];
#pragma unroll
    for (int i = 0; i < 2; ++i) {
      int q = tid + 256 * i;
      int r = q >> 3, c = q & 7;
      int rg = row0 + r;
      rg = rg < CN1 ? rg : CN1 - 1;
      av[i] = *reinterpret_cast<const int4*>(Asrc + (size_t)rg * CD_IN + koff + c * 8);
    }
    // W1 tile: 256 rows x 64 k = 2048 int4 -> 8/thread
    int4 wv[8];
#pragma unroll
    for (int i = 0; i < 8; ++i) {
      int q = tid + 256 * i;
      int r = q >> 3, c = q & 7;
      wv[i] = *reinterpret_cast<const int4*>(wcat + (size_t)r * 256 + k0 + c * 8);
    }
    __syncthreads();
#pragma unroll
    for (int i = 0; i < 2; ++i) {
      int q = tid + 256 * i;
      int r = q >> 3, c = q & 7;
      *reinterpret_cast<int4*>(&As[r * 72 + c * 8]) = av[i];
    }
#pragma unroll
    for (int i = 0; i < 8; ++i) {
      int q = tid + 256 * i;
      int r = q >> 3, c = q & 7;
      *reinterpret_cast<int4*>(&Ws[r * 72 + c * 8]) = wv[i];
    }
    __syncthreads();

#pragma unroll
    for (int ks = 0; ks < 2; ++ks) {
      const int kb = ks * 32 + lr * 8;
      bf16x8 af = *reinterpret_cast<const bf16x8*>(&As[(w * 16 + lc) * 72 + kb]);
#pragma unroll
      for (int n = 0; n < 16; ++n) {
        bf16x8 bfv = *reinterpret_cast<const bf16x8*>(&Ws[(n * 16 + lc) * 72 + kb]);
        acc1[n] = __builtin_amdgcn_mfma_f32_16x16x32_bf16(af, bfv, acc1[n], 0, 0, 0);
      }
    }
    __syncthreads();  // all waves done reading As/Ws before next-tile overwrite
  }

  // epilogue 1: bias + relu -> bf16 -> h1s (each wave writes only its own rows)
#pragma unroll
  for (int n = 0; n < 16; ++n) {
    float bb = bias[n * 16 + lc];
#pragma unroll
    for (int i = 0; i < 4; ++i) {
      float v = fmaxf(acc1[n][i] + bb, 0.0f);
      h1s[(w * 16 + lr * 4 + i) * 264 + n * 16 + lc] = f2bf(v);
    }
  }

  // ---- phase 2: [t2 | out_part] = h1 @ W2cat^T ----
  f32x4 acc2[8];
#pragma unroll
  for (int n = 0; n < 8; ++n) acc2[n] = (f32x4)0.0f;

  for (int t = 0; t < 4; ++t) {
    const int k0 = t * 64;
    // W2 tile: 128 rows x 64 k = 1024 int4 -> 4/thread
    int4 wv[4];
#pragma unroll
    for (int i = 0; i < 4; ++i) {
      int q = tid + 256 * i;
      int r = q >> 3, c = q & 7;
      wv[i] = *reinterpret_cast<const int4*>(w2cat + (size_t)r * 256 + k0 + c * 8);
    }
    __syncthreads();  // waves done with Ws (phase1) / previous W2 tile
#pragma unroll
    for (int i = 0; i < 4; ++i) {
      int q = tid + 256 * i;
      int r = q >> 3, c = q & 7;
      *reinterpret_cast<int4*>(&Ws[r * 72 + c * 8]) = wv[i];
    }
    __syncthreads();

#pragma unroll
    for (int ks = 0; ks < 2; ++ks) {
      const int kb = ks * 32 + lr * 8;
      bf16x8 af = *reinterpret_cast<const bf16x8*>(&h1s[(w * 16 + lc) * 264 + k0 + kb]);
#pragma unroll
      for (int n = 0; n < 8; ++n) {
        bf16x8 bfv = *reinterpret_cast<const bf16x8*>(&Ws[(n * 16 + lc) * 72 + kb]);
        acc2[n] = __builtin_amdgcn_mfma_f32_16x16x32_bf16(af, bfv, acc2[n], 0, 0, 0);
      }
    }
  }

  // epilogue 2: t2 (bf16) for all rows < N1; out partial (f32) for rows < N2
#pragma unroll
  for (int i = 0; i < 4; ++i) {
    int rg = row0 + w * 16 + lr * 4 + i;
    if (rg < CN1) {
#pragma unroll
      for (int n = 0; n < 4; ++n)
        t2[(size_t)rg * CD_OUT + n * 16 + lc] = f2bf(acc2[n][i]);
      if (rg < CN2) {
#pragma unroll
        for (int n = 0; n < 4; ++n)
          outp[(size_t)rg * CD_OUT + n * 16 + lc] = acc2[n + 4][i];
      }
    }
  }
}

// ---------------- finalize: out = log_softmax(out + agg2 + b2) ----------------
__global__ __launch_bounds__(256) void sage_finalize(
    const float* __restrict__ agg2, const float* __restrict__ b,
    float* __restrict__ out) {
  int row = blockIdx.x * 4 + (threadIdx.x >> 6);
  int lane = threadIdx.x & 63;
  if (row >= CN2) return;
  size_t o = (size_t)row * CD_OUT + lane;
  float v = out[o] + agg2[o] + b[lane];
  float m = v;
#pragma unroll
  for (int d = 32; d > 0; d >>= 1) m = fmaxf(m, __shfl_xor(m, d));
  float e = expf(v - m);
  float s = e;
#pragma unroll
  for (int d = 32; d > 0; d >>= 1) s += __shfl_xor(s, d);
  out[o] = v - m - logf(s);
}

extern "C" void kernel_launch(void* const* d_in, const int* in_sizes, int n_in,
                              void* d_out, int out_size, void* d_ws, size_t ws_size,
                              hipStream_t stream) {
  const float* x    = (const float*)d_in[0];
  const int* src1   = (const int*)d_in[1];
  const int* dst1   = (const int*)d_in[2];
  const int* src2   = (const int*)d_in[3];
  const int* dst2   = (const int*)d_in[4];
  const float* W_l1 = (const float*)d_in[5];
  const float* b_l1 = (const float*)d_in[6];
  const float* W_r1 = (const float*)d_in[7];
  const float* W_l2 = (const float*)d_in[8];
  const float* b_l2 = (const float*)d_in[9];
  const float* W_r2 = (const float*)d_in[10];
  float* out = (float*)d_out;
  char* base = (char*)d_ws;

  // ---- workspace layout (bytes), total 135,797,632 ----
  // [0, 51.2M)        x_bf    [N0][128] bf16
  // [51.2M, 64.0M)    t2_bf   [N1][64]  bf16
  // [102.4M, 128.0M)  Rreg:
  //     phase A: agg_bf [N1][128] bf16 (dead after mega)
  //     phase B: agg2 f32 at +12.8M (5.12M) | CSR2 ints at +17.92M
  // [128.0M, 135.6M)  CSR1 ints: deg1,R1,cur1 (3x400K), part1(1K), esrc1(6.4M)
  // [135.6M, 135.8M)  bf16 weights: Wcat[256][256], W2cat[128][256]
  uint16_t* x_bf  = (uint16_t*)base;
  uint16_t* t2_bf = (uint16_t*)(base + 51200000);
  char* Rreg = base + 102400000;
  uint16_t* agg_bf = (uint16_t*)Rreg;
  float* agg2 = (float*)(Rreg + 12800000);
  int* deg2 = (int*)(Rreg + 17920000);
  int* R2   = deg2 + CN2;
  int* cur2 = R2 + CN2;
  int* part2 = cur2 + CN2;
  int* esrc2 = part2 + 256;
  char* csr1 = base + 128000000;
  int* deg1 = (int*)csr1;
  int* R1   = deg1 + CN1;
  int* cur1 = R1 + CN1;
  int* part1 = cur1 + CN1;
  int* esrc1 = part1 + 256;
  uint16_t* wcat  = (uint16_t*)(base + 135601024);
  uint16_t* w2cat = wcat + 65536;   // rows 0..63 = W_l2, rows 64..127 = W_r2

  if (ws_size < 135797632u) return;

  const int B1 = (CN1 + 511) / 512;  // 196
  const int B2 = (CN2 + 511) / 512;  // 40

  // ---- converts ----
  cvt_f32_bf16_v4<<<(CN0 * CD_IN / 4 + 255) / 256, 256, 0, stream>>>(x, x_bf, CN0 * CD_IN / 4);
  cvt_wcat<<<256, 256, 0, stream>>>(W_l1, W_r1, wcat);
  cvt_small<<<64, 256, 0, stream>>>(W_l2, w2cat, CD_OUT * CD_H);
  cvt_small<<<64, 256, 0, stream>>>(W_r2, w2cat + 16384, CD_OUT * CD_H);

  // ---- layer 1 CSR + gather ----
  hipMemsetAsync(deg1, 0, CN1 * sizeof(int), stream);
  sage_hist<<<(CE1 + 255) / 256, 256, 0, stream>>>(dst1, deg1, CE1);
  sage_scan_local<<<B1, 256, 0, stream>>>(deg1, R1, part1, CN1);
  sage_scan_part<<<1, 256, 0, stream>>>(part1, B1);
  sage_addback<<<(CN1 + 255) / 256, 256, 0, stream>>>(R1, cur1, part1, CN1);
  sage_place<<<(CE1 + 255) / 256, 256, 0, stream>>>(src1, dst1, cur1, esrc1, CE1);
  sage_gather1<<<(CN1 + 3) / 4, 256, 0, stream>>>(x_bf, esrc1, R1, deg1, agg_bf);

  // ---- mega: h1 in LDS; writes t2 + out-partial ----
  sage_mega<<<(CN1 + 63) / 64, 256, 0, stream>>>(
      agg_bf, x_bf, wcat, w2cat, b_l1, t2_bf, out);

  // ---- layer 2 CSR + gather ----
  hipMemsetAsync(deg2, 0, CN2 * sizeof(int), stream);
  sage_hist<<<(CE2 + 255) / 256, 256, 0, stream>>>(dst2, deg2, CE2);
  sage_scan_local<<<B2, 256, 0, stream>>>(deg2, R2, part2, CN2);
  sage_scan_part<<<1, 256, 0, stream>>>(part2, B2);
  sage_addback<<<(CN2 + 255) / 256, 256, 0, stream>>>(R2, cur2, part2, CN2);
  sage_place<<<(CE2 + 255) / 256, 256, 0, stream>>>(src2, dst2, cur2, esrc2, CE2);
  sage_gather2<<<(CN2 + 7) / 8, 256, 0, stream>>>(t2_bf, esrc2, R2, deg2, agg2);

  // ---- finalize ----
  sage_finalize<<<(CN2 + 3) / 4, 256, 0, stream>>>(agg2, b_l2, out);
}